// Round 1
// baseline (387.244 us; speedup 1.0000x reference)
//
#include <hip/hip_runtime.h>

// Problem constants (bert-base KG embedding)
#define VV   30522
#define HH   768
#define BB   32
#define SS   512
#define EE   8
#define KGD  100
#define MHID 1000

#define NDT  12          // d-tiles of 64 columns: 12*64 = 768

// ---------------------------------------------------------------------------
// Kernel 1: entity MLP  ent[b,e,:] = relu(ee[b,e,:] @ W1 + b1) @ W2 + b2
// grid = B * NDT blocks; block = 256 threads.
// Each block: batch b, output-column tile of 64.
//   stage 1: all 8 entities' h[1000] in LDS (redundant across d-tiles, cheap)
//   stage 2: 4 groups of 64 lanes; group g computes entities {2g, 2g+1},
//            sharing each W2 load across both entities.
// ---------------------------------------------------------------------------
__global__ __launch_bounds__(256) void mlp_kernel(
    const float* __restrict__ ee,   // [B,E,KGD]
    const float* __restrict__ W1,   // [KGD,MHID]
    const float* __restrict__ b1,   // [MHID]
    const float* __restrict__ W2,   // [MHID,HH]
    const float* __restrict__ b2,   // [HH]
    float* __restrict__ ent)        // [B,E,HH] (workspace)
{
    __shared__ float sEE[EE * KGD];    // 800 floats
    __shared__ float sH[EE * MHID];    // 8000 floats = 32 KB

    const int b  = blockIdx.x / NDT;
    const int dt = blockIdx.x % NDT;
    const int tid = threadIdx.x;

    // stage ee for this batch
    for (int i = tid; i < EE * KGD; i += 256)
        sEE[i] = ee[b * EE * KGD + i];
    __syncthreads();

    // stage 1: h[e][j] = relu(sum_k ee[e][k] * W1[k][j] + b1[j])
    for (int idx = tid; idx < EE * MHID; idx += 256) {
        const int e = idx / MHID;
        const int j = idx - e * MHID;
        float acc = b1[j];
        const float* eeRow = &sEE[e * KGD];
        #pragma unroll 4
        for (int k = 0; k < KGD; ++k)
            acc = fmaf(eeRow[k], W1[k * MHID + j], acc);
        sH[idx] = fmaxf(acc, 0.0f);
    }
    __syncthreads();

    // stage 2: ent[e][d] = sum_j h[e][j] * W2[j][d] + b2[d]
    const int c  = tid & 63;       // column within tile
    const int g  = tid >> 6;       // group 0..3
    const int e0 = 2 * g;
    const int e1 = 2 * g + 1;
    const int d  = dt * 64 + c;

    float acc0 = b2[d];
    float acc1 = acc0;
    const float* h0 = &sH[e0 * MHID];
    const float* h1 = &sH[e1 * MHID];
    #pragma unroll 8
    for (int j = 0; j < MHID; ++j) {
        const float w = W2[j * HH + d];
        acc0 = fmaf(h0[j], w, acc0);
        acc1 = fmaf(h1[j], w, acc1);
    }
    ent[(b * EE + e0) * HH + d] = acc0;
    ent[(b * EE + e1) * HH + d] = acc1;
}

// ---------------------------------------------------------------------------
// Kernel 2: out[b,s,:] = word_embedding[ids[b,s],:] + sum_e mask[b,e,s]*ent[b,e,:]
// grid = B*S blocks; block = 192 threads (3 waves); float4 per thread.
// mask value is uniform per (block, e) -> uniform branch, no divergence.
// ---------------------------------------------------------------------------
__global__ __launch_bounds__(192) void gather_scatter_kernel(
    const int*   __restrict__ ids,   // [B,S]
    const float* __restrict__ mask,  // [B,E,S]
    const float* __restrict__ we,    // [V,H]
    const float* __restrict__ ent,   // [B,E,H]
    float* __restrict__ out)         // [B,S,H]
{
    const int row = blockIdx.x;          // b*S + s
    const int b   = row >> 9;            // / 512
    const int s   = row & (SS - 1);
    const int t   = threadIdx.x;         // 0..191

    const int id = ids[row];
    float4 v = reinterpret_cast<const float4*>(we + (long)id * HH)[t];

    const float* mrow = mask + ((long)b * EE) * SS + s;  // stride SS per e
    #pragma unroll
    for (int e = 0; e < EE; ++e) {
        const float m = mrow[e * SS];
        if (m != 0.0f) {
            const float4 ev =
                reinterpret_cast<const float4*>(ent + ((b * EE + e) * HH))[t];
            v.x = fmaf(m, ev.x, v.x);
            v.y = fmaf(m, ev.y, v.y);
            v.z = fmaf(m, ev.z, v.z);
            v.w = fmaf(m, ev.w, v.w);
        }
    }
    reinterpret_cast<float4*>(out + (long)row * HH)[t] = v;
}

extern "C" void kernel_launch(void* const* d_in, const int* in_sizes, int n_in,
                              void* d_out, int out_size, void* d_ws, size_t ws_size,
                              hipStream_t stream) {
    const int*   input_ids = (const int*)  d_in[0];
    const float* ent_emb   = (const float*)d_in[1];
    const float* ent_mask  = (const float*)d_in[2];
    const float* word_emb  = (const float*)d_in[3];
    const float* W1        = (const float*)d_in[4];
    const float* b1        = (const float*)d_in[5];
    const float* W2        = (const float*)d_in[6];
    const float* b2        = (const float*)d_in[7];
    float*       out       = (float*)d_out;

    float* ent = (float*)d_ws;   // [B*E*H] = 786432 bytes

    mlp_kernel<<<dim3(BB * NDT), dim3(256), 0, stream>>>(
        ent_emb, W1, b1, W2, b2, ent);

    gather_scatter_kernel<<<dim3(BB * SS), dim3(192), 0, stream>>>(
        input_ids, ent_mask, word_emb, ent, out);
}

// Round 2
// 220.670 us; speedup vs baseline: 1.7549x; 1.7549x over previous
//
#include <hip/hip_runtime.h>

// Problem constants (bert-base KG embedding)
#define VV   30522
#define HH   768
#define BB   32
#define SS   512
#define EE   8
#define KGD  100
#define MHID 1000

#define RTOT (BB * EE)        // 256 entity rows
#define KS   5                // K-split for stage 2
#define KC   (MHID / KS)      // 200 per chunk

// ---------------------------------------------------------------------------
// Kernel 1: h[r,:] = relu(ee[r,:] @ W1 + b1), r = b*E+e  (256 rows)
//           also initializes ent[r,:] = b2  (so mlp2 can atomicAdd)
// grid = 256 blocks (one per row), block = 256.
// Thread t computes j in {t, t+256, t+512, t+768} (last predicated).
// W1 loads coalesced across lanes; 4 indep acc chains, k-unroll 2 -> ILP 8.
// ---------------------------------------------------------------------------
__global__ __launch_bounds__(256) void mlp1_kernel(
    const float* __restrict__ ee,   // [256,KGD]
    const float* __restrict__ W1,   // [KGD,MHID]
    const float* __restrict__ b1,   // [MHID]
    const float* __restrict__ b2,   // [HH]
    float* __restrict__ h,          // [256,MHID] ws
    float* __restrict__ ent)        // [256,HH]   ws
{
    __shared__ float sEE[KGD];
    const int r   = blockIdx.x;
    const int tid = threadIdx.x;

    for (int i = tid; i < KGD; i += 256)
        sEE[i] = ee[r * KGD + i];

    // init ent row with b2 (mlp2 accumulates on top)
    for (int i = tid; i < HH; i += 256)
        ent[r * HH + i] = b2[i];
    __syncthreads();

    const int j0 = tid;
    const int j1 = tid + 256;
    const int j2 = tid + 512;
    const int j3v = tid + 768;
    const bool v3 = (j3v < MHID);
    const int j3 = v3 ? j3v : (MHID - 1);   // harmless clamped load

    float a0 = b1[j0], a1 = b1[j1], a2 = b1[j2], a3 = b1[j3];
    #pragma unroll 2
    for (int k = 0; k < KGD; ++k) {
        const float x = sEE[k];
        const float* w = &W1[k * MHID];
        a0 = fmaf(x, w[j0], a0);
        a1 = fmaf(x, w[j1], a1);
        a2 = fmaf(x, w[j2], a2);
        a3 = fmaf(x, w[j3], a3);
    }
    float* hr = &h[r * MHID];
    hr[j0] = fmaxf(a0, 0.0f);
    hr[j1] = fmaxf(a1, 0.0f);
    hr[j2] = fmaxf(a2, 0.0f);
    if (v3) hr[j3] = fmaxf(a3, 0.0f);
}

// ---------------------------------------------------------------------------
// Kernel 2: ent[b*E+e, d] += sum_j h[b*E+e, j] * W2[j, d]   (K-split atomics)
// grid = (12 dtiles * KS kchunks, 32 batches), block = 256.
// Thread (c = tid&63, g = tid>>6): col d = dt*64+c, entities {2g, 2g+1},
// sharing each W2 load across 2 FMAs. h-chunk [8][KC] staged in LDS.
// ---------------------------------------------------------------------------
__global__ __launch_bounds__(256) void mlp2_kernel(
    const float* __restrict__ h,    // [256,MHID]
    const float* __restrict__ W2,   // [MHID,HH]
    float* __restrict__ ent)        // [256,HH]
{
    __shared__ float sH[EE * KC];   // 8*200 floats = 6.4 KB

    const int dt = blockIdx.x / KS;
    const int kc = blockIdx.x % KS;
    const int b  = blockIdx.y;
    const int tid = threadIdx.x;

    for (int i = tid; i < EE * KC; i += 256) {
        const int e = i / KC;
        const int j = i - e * KC;
        sH[i] = h[(b * EE + e) * MHID + kc * KC + j];
    }
    __syncthreads();

    const int c  = tid & 63;
    const int g  = tid >> 6;
    const int e0 = 2 * g;
    const int d  = dt * 64 + c;

    float acc0 = 0.0f, acc1 = 0.0f;
    const float* h0 = &sH[e0 * KC];
    const float* h1 = &sH[(e0 + 1) * KC];
    const float* w  = &W2[(size_t)(kc * KC) * HH + d];
    #pragma unroll 4
    for (int j = 0; j < KC; ++j) {
        const float wv = w[(size_t)j * HH];
        acc0 = fmaf(h0[j], wv, acc0);
        acc1 = fmaf(h1[j], wv, acc1);
    }
    atomicAdd(&ent[(b * EE + e0) * HH + d], acc0);
    atomicAdd(&ent[(b * EE + e0 + 1) * HH + d], acc1);
}

// ---------------------------------------------------------------------------
// Kernel 3: out[row,:] = we[ids[row],:] + sum_e mask[b,e,s]*ent[b*E+e,:]
// 64 lanes per row, 3 float4 per lane; 4 rows per 256-thread block.
// grid = B*S/4 = 4096 blocks.
// ---------------------------------------------------------------------------
__global__ __launch_bounds__(256) void gather_scatter_kernel(
    const int*   __restrict__ ids,   // [B,S]
    const float* __restrict__ mask,  // [B,E,S]
    const float* __restrict__ we,    // [V,H]
    const float* __restrict__ ent,   // [B*E,H]
    float* __restrict__ out)         // [B,S,H]
{
    const int row = blockIdx.x * 4 + (threadIdx.x >> 6);
    const int l   = threadIdx.x & 63;
    const int b   = row >> 9;
    const int s   = row & (SS - 1);

    const int id = ids[row];
    const float4* wrow = reinterpret_cast<const float4*>(we + (size_t)id * HH);
    float4 v0 = wrow[l];
    float4 v1 = wrow[l + 64];
    float4 v2 = wrow[l + 128];

    const float* mrow = mask + (size_t)b * EE * SS + s;
    #pragma unroll
    for (int e = 0; e < EE; ++e) {
        const float m = mrow[e * SS];
        if (m != 0.0f) {   // uniform across the wave (same row)
            const float4* er =
                reinterpret_cast<const float4*>(ent + (size_t)(b * EE + e) * HH);
            const float4 e0 = er[l], e1 = er[l + 64], e2 = er[l + 128];
            v0.x = fmaf(m, e0.x, v0.x); v0.y = fmaf(m, e0.y, v0.y);
            v0.z = fmaf(m, e0.z, v0.z); v0.w = fmaf(m, e0.w, v0.w);
            v1.x = fmaf(m, e1.x, v1.x); v1.y = fmaf(m, e1.y, v1.y);
            v1.z = fmaf(m, e1.z, v1.z); v1.w = fmaf(m, e1.w, v1.w);
            v2.x = fmaf(m, e2.x, v2.x); v2.y = fmaf(m, e2.y, v2.y);
            v2.z = fmaf(m, e2.z, v2.z); v2.w = fmaf(m, e2.w, v2.w);
        }
    }
    float4* orow = reinterpret_cast<float4*>(out + (size_t)row * HH);
    orow[l]       = v0;
    orow[l + 64]  = v1;
    orow[l + 128] = v2;
}

extern "C" void kernel_launch(void* const* d_in, const int* in_sizes, int n_in,
                              void* d_out, int out_size, void* d_ws, size_t ws_size,
                              hipStream_t stream) {
    const int*   input_ids = (const int*)  d_in[0];
    const float* ent_emb   = (const float*)d_in[1];
    const float* ent_mask  = (const float*)d_in[2];
    const float* word_emb  = (const float*)d_in[3];
    const float* W1        = (const float*)d_in[4];
    const float* b1        = (const float*)d_in[5];
    const float* W2        = (const float*)d_in[6];
    const float* b2        = (const float*)d_in[7];
    float*       out       = (float*)d_out;

    float* ent = (float*)d_ws;                       // [256*768]  = 768 KB
    float* h   = (float*)d_ws + (size_t)RTOT * HH;   // [256*1000] = 1000 KB

    mlp1_kernel<<<dim3(RTOT), dim3(256), 0, stream>>>(
        ent_emb, W1, b1, b2, h, ent);

    mlp2_kernel<<<dim3(12 * KS, BB), dim3(256), 0, stream>>>(
        h, W2, ent);

    gather_scatter_kernel<<<dim3(BB * SS / 4), dim3(256), 0, stream>>>(
        input_ids, ent_mask, word_emb, ent, out);
}

// Round 5
// 207.464 us; speedup vs baseline: 1.8666x; 1.0637x over previous
//
#include <hip/hip_runtime.h>

// Problem constants (bert-base KG embedding)
#define VV   30522
#define HH   768
#define BB   32
#define SS   512
#define EE   8
#define KGD  100
#define MHID 1000

#define RTOT (BB * EE)        // 256 entity rows
#define KS   8                // K-split for stage 2
#define KC   (MHID / KS)      // 125 per chunk

typedef float f32x4 __attribute__((ext_vector_type(4)));

// ---------------------------------------------------------------------------
// Kernel 1: h[r,:] = relu(ee[r,:] @ W1 + b1)   (256 rows)
//           also initializes ent[r,:] = b2 (half per y-block)
// grid = (256, 2), block = 256. y-block jc covers j in [jc*512, jc*512+512).
// Thread t: j ∈ {jc*512+t, jc*512+t+256} (clamped at 1000). 2 acc chains,
// unroll 4 -> 8 independent W1 loads in flight. 512 blocks = 2/CU.
// ---------------------------------------------------------------------------
__global__ __launch_bounds__(256) void mlp1_kernel(
    const float* __restrict__ ee,   // [256,KGD]
    const float* __restrict__ W1,   // [KGD,MHID]
    const float* __restrict__ b1,   // [MHID]
    const float* __restrict__ b2,   // [HH]
    float* __restrict__ h,          // [256,MHID] ws
    float* __restrict__ ent)        // [256,HH]   ws
{
    __shared__ float sEE[KGD];
    const int r   = blockIdx.x;
    const int jc  = blockIdx.y;          // 0 or 1
    const int tid = threadIdx.x;

    if (tid < KGD) sEE[tid] = ee[r * KGD + tid];

    // init ent row with b2 (this y-block's half: 384 cols)
    {
        const int base = jc * (HH / 2);
        for (int i = tid; i < HH / 2; i += 256)
            ent[r * HH + base + i] = b2[base + i];
    }
    __syncthreads();

    const int j0  = jc * 512 + tid;            // always < 1000
    const int j1v = jc * 512 + tid + 256;
    const bool v1 = (j1v < MHID);
    const int j1  = v1 ? j1v : (MHID - 1);     // clamped (harmless load)

    float a0 = b1[j0];
    float a1 = b1[j1];
    #pragma unroll 4
    for (int k = 0; k < KGD; ++k) {
        const float x = sEE[k];
        const float* w = &W1[k * MHID];
        a0 = fmaf(x, w[j0], a0);
        a1 = fmaf(x, w[j1], a1);
    }
    float* hr = &h[r * MHID];
    hr[j0] = fmaxf(a0, 0.0f);
    if (v1) hr[j1] = fmaxf(a1, 0.0f);
}

// ---------------------------------------------------------------------------
// Kernel 2: ent[b*E+e, d] += sum_j h[b*E+e, j] * W2[j, d]   (K-split atomics)
// grid = (12 dtiles * KS kchunks, 32 batches) = 3072 blocks (12/CU), blk 256.
// Thread (c = tid&63, g = tid>>6): col d = dt*64+c, entities {2g, 2g+1},
// sharing each W2 load across 2 FMAs. h-chunk [8][KC] staged in LDS.
// ---------------------------------------------------------------------------
__global__ __launch_bounds__(256) void mlp2_kernel(
    const float* __restrict__ h,    // [256,MHID]
    const float* __restrict__ W2,   // [MHID,HH]
    float* __restrict__ ent)        // [256,HH]
{
    __shared__ float sH[EE * KC];   // 8*125 floats = 4 KB

    const int dt = blockIdx.x / KS;
    const int kc = blockIdx.x % KS;
    const int b  = blockIdx.y;
    const int tid = threadIdx.x;

    for (int i = tid; i < EE * KC; i += 256) {
        const int e = i / KC;
        const int j = i - e * KC;
        sH[i] = h[(b * EE + e) * MHID + kc * KC + j];
    }
    __syncthreads();

    const int c  = tid & 63;
    const int g  = tid >> 6;
    const int e0 = 2 * g;
    const int d  = dt * 64 + c;

    float acc0 = 0.0f, acc1 = 0.0f;
    const float* h0 = &sH[e0 * KC];
    const float* h1 = &sH[(e0 + 1) * KC];
    const float* w  = &W2[(size_t)(kc * KC) * HH + d];
    #pragma unroll 5
    for (int j = 0; j < KC; ++j) {
        const float wv = w[(size_t)j * HH];
        acc0 = fmaf(h0[j], wv, acc0);
        acc1 = fmaf(h1[j], wv, acc1);
    }
    atomicAdd(&ent[(b * EE + e0) * HH + d], acc0);
    atomicAdd(&ent[(b * EE + e0 + 1) * HH + d], acc1);
}

// ---------------------------------------------------------------------------
// Kernel 3: out[row,:] = we[ids[row],:] + sum_e mask[b,e,s]*ent[b*E+e,:]
// 64 lanes per row, 3 f32x4 per lane; 4 rows per 256-thread block.
// grid = B*S/4 = 4096 blocks. Nontemporal stores (out never re-read).
// ---------------------------------------------------------------------------
__global__ __launch_bounds__(256) void gather_scatter_kernel(
    const int*   __restrict__ ids,   // [B,S]
    const float* __restrict__ mask,  // [B,E,S]
    const float* __restrict__ we,    // [V,H]
    const float* __restrict__ ent,   // [B*E,H]
    float* __restrict__ out)         // [B,S,H]
{
    const int row = blockIdx.x * 4 + (threadIdx.x >> 6);
    const int l   = threadIdx.x & 63;
    const int b   = row >> 9;
    const int s   = row & (SS - 1);

    const int id = ids[row];
    const f32x4* wrow = reinterpret_cast<const f32x4*>(we + (size_t)id * HH);
    f32x4 v0 = wrow[l];
    f32x4 v1 = wrow[l + 64];
    f32x4 v2 = wrow[l + 128];

    const float* mrow = mask + (size_t)b * EE * SS + s;
    #pragma unroll
    for (int e = 0; e < EE; ++e) {
        const float m = mrow[e * SS];
        if (m != 0.0f) {   // uniform across the wave (same row)
            const f32x4* er =
                reinterpret_cast<const f32x4*>(ent + (size_t)(b * EE + e) * HH);
            const f32x4 e0 = er[l], e1 = er[l + 64], e2 = er[l + 128];
            v0 += m * e0;
            v1 += m * e1;
            v2 += m * e2;
        }
    }
    f32x4* orow = reinterpret_cast<f32x4*>(out + (size_t)row * HH);
    __builtin_nontemporal_store(v0, &orow[l]);
    __builtin_nontemporal_store(v1, &orow[l + 64]);
    __builtin_nontemporal_store(v2, &orow[l + 128]);
}

extern "C" void kernel_launch(void* const* d_in, const int* in_sizes, int n_in,
                              void* d_out, int out_size, void* d_ws, size_t ws_size,
                              hipStream_t stream) {
    const int*   input_ids = (const int*)  d_in[0];
    const float* ent_emb   = (const float*)d_in[1];
    const float* ent_mask  = (const float*)d_in[2];
    const float* word_emb  = (const float*)d_in[3];
    const float* W1        = (const float*)d_in[4];
    const float* b1        = (const float*)d_in[5];
    const float* W2        = (const float*)d_in[6];
    const float* b2        = (const float*)d_in[7];
    float*       out       = (float*)d_out;

    float* ent = (float*)d_ws;                       // [256*768]  = 768 KB
    float* h   = (float*)d_ws + (size_t)RTOT * HH;   // [256*1000] = 1000 KB

    mlp1_kernel<<<dim3(RTOT, 2), dim3(256), 0, stream>>>(
        ent_emb, W1, b1, b2, h, ent);

    mlp2_kernel<<<dim3(12 * KS, BB), dim3(256), 0, stream>>>(
        h, W2, ent);

    gather_scatter_kernel<<<dim3(BB * SS / 4), dim3(256), 0, stream>>>(
        input_ids, ent_mask, word_emb, ent, out);
}

// Round 7
// 206.857 us; speedup vs baseline: 1.8720x; 1.0029x over previous
//
#include <hip/hip_runtime.h>

// Problem constants (bert-base KG embedding)
#define VV   30522
#define HH   768
#define BB   32
#define SS   512
#define EE   8
#define KGD  100
#define MHID 1000

#define RTOT (BB * EE)        // 256 entity rows
#define KS   8                // K-split for stage 2
#define KC   (MHID / KS)      // 125 per chunk

typedef float f32x4 __attribute__((ext_vector_type(4)));

// ---------------------------------------------------------------------------
// Kernel 1: h[r,:] = relu(ee[r,:] @ W1 + b1)   (256 rows)
//           also initializes ent[r,:] = b2 (half per y-block)
// grid = (256, 2), block = 256. 2 acc chains, unroll 4 -> 8 loads in flight.
// ---------------------------------------------------------------------------
__global__ __launch_bounds__(256) void mlp1_kernel(
    const float* __restrict__ ee,   // [256,KGD]
    const float* __restrict__ W1,   // [KGD,MHID]
    const float* __restrict__ b1,   // [MHID]
    const float* __restrict__ b2,   // [HH]
    float* __restrict__ h,          // [256,MHID] ws
    float* __restrict__ ent)        // [256,HH]   ws
{
    __shared__ float sEE[KGD];
    const int r   = blockIdx.x;
    const int jc  = blockIdx.y;          // 0 or 1
    const int tid = threadIdx.x;

    if (tid < KGD) sEE[tid] = ee[r * KGD + tid];

    // init ent row with b2 (this y-block's half: 384 cols)
    {
        const int base = jc * (HH / 2);
        for (int i = tid; i < HH / 2; i += 256)
            ent[r * HH + base + i] = b2[base + i];
    }
    __syncthreads();

    const int j0  = jc * 512 + tid;            // always < 1000
    const int j1v = jc * 512 + tid + 256;
    const bool v1 = (j1v < MHID);
    const int j1  = v1 ? j1v : (MHID - 1);     // clamped (harmless load)

    float a0 = b1[j0];
    float a1 = b1[j1];
    #pragma unroll 4
    for (int k = 0; k < KGD; ++k) {
        const float x = sEE[k];
        const float* w = &W1[k * MHID];
        a0 = fmaf(x, w[j0], a0);
        a1 = fmaf(x, w[j1], a1);
    }
    float* hr = &h[r * MHID];
    hr[j0] = fmaxf(a0, 0.0f);
    if (v1) hr[j1] = fmaxf(a1, 0.0f);
}

// ---------------------------------------------------------------------------
// Kernel 2: ent[b*E+e, d] += sum_j h[b*E+e, j] * W2[j, d]   (K-split atomics)
// grid = (12 dtiles * KS kchunks, 32 batches) = 3072 blocks, blk 256.
// ---------------------------------------------------------------------------
__global__ __launch_bounds__(256) void mlp2_kernel(
    const float* __restrict__ h,    // [256,MHID]
    const float* __restrict__ W2,   // [MHID,HH]
    float* __restrict__ ent)        // [256,HH]
{
    __shared__ float sH[EE * KC];   // 8*125 floats = 4 KB

    const int dt = blockIdx.x / KS;
    const int kc = blockIdx.x % KS;
    const int b  = blockIdx.y;
    const int tid = threadIdx.x;

    for (int i = tid; i < EE * KC; i += 256) {
        const int e = i / KC;
        const int j = i - e * KC;
        sH[i] = h[(b * EE + e) * MHID + kc * KC + j];
    }
    __syncthreads();

    const int c  = tid & 63;
    const int g  = tid >> 6;
    const int e0 = 2 * g;
    const int d  = dt * 64 + c;

    float acc0 = 0.0f, acc1 = 0.0f;
    const float* h0 = &sH[e0 * KC];
    const float* h1 = &sH[(e0 + 1) * KC];
    const float* w  = &W2[(size_t)(kc * KC) * HH + d];
    #pragma unroll 5
    for (int j = 0; j < KC; ++j) {
        const float wv = w[(size_t)j * HH];
        acc0 = fmaf(h0[j], wv, acc0);
        acc1 = fmaf(h1[j], wv, acc1);
    }
    atomicAdd(&ent[(b * EE + e0) * HH + d], acc0);
    atomicAdd(&ent[(b * EE + e0 + 1) * HH + d], acc1);
}

// ---------------------------------------------------------------------------
// Kernel 3: out[row,:] = we[ids[row],:] + sum_e mask[b,e,s]*ent[b*E+e,:]
// 64 lanes per row, 3 f32x4 per lane; 4 rows per 256-thread block.
// Mask scalars preloaded BEFORE the gather row loads (overlap latency).
// grid = B*S/4 = 4096 blocks. Nontemporal stores (out never re-read).
// ---------------------------------------------------------------------------
__global__ __launch_bounds__(256) void gather_scatter_kernel(
    const int*   __restrict__ ids,   // [B,S]
    const float* __restrict__ mask,  // [B,E,S]
    const float* __restrict__ we,    // [V,H]
    const float* __restrict__ ent,   // [B*E,H]
    float* __restrict__ out)         // [B,S,H]
{
    const int row = blockIdx.x * 4 + (threadIdx.x >> 6);
    const int l   = threadIdx.x & 63;
    const int b   = row >> 9;
    const int s   = row & (SS - 1);

    const int id = ids[row];

    // issue all 8 mask loads up front; they complete under the we-row latency
    const float* mrow = mask + (size_t)b * EE * SS + s;
    float mv[EE];
    #pragma unroll
    for (int e = 0; e < EE; ++e) mv[e] = mrow[e * SS];

    const f32x4* wrow = reinterpret_cast<const f32x4*>(we + (size_t)id * HH);
    f32x4 v0 = wrow[l];
    f32x4 v1 = wrow[l + 64];
    f32x4 v2 = wrow[l + 128];

    #pragma unroll
    for (int e = 0; e < EE; ++e) {
        const float m = mv[e];
        if (m != 0.0f) {   // uniform across the wave (same row)
            const f32x4* er =
                reinterpret_cast<const f32x4*>(ent + (size_t)(b * EE + e) * HH);
            const f32x4 e0 = er[l], e1 = er[l + 64], e2 = er[l + 128];
            v0 += m * e0;
            v1 += m * e1;
            v2 += m * e2;
        }
    }
    f32x4* orow = reinterpret_cast<f32x4*>(out + (size_t)row * HH);
    __builtin_nontemporal_store(v0, &orow[l]);
    __builtin_nontemporal_store(v1, &orow[l + 64]);
    __builtin_nontemporal_store(v2, &orow[l + 128]);
}

extern "C" void kernel_launch(void* const* d_in, const int* in_sizes, int n_in,
                              void* d_out, int out_size, void* d_ws, size_t ws_size,
                              hipStream_t stream) {
    const int*   input_ids = (const int*)  d_in[0];
    const float* ent_emb   = (const float*)d_in[1];
    const float* ent_mask  = (const float*)d_in[2];
    const float* word_emb  = (const float*)d_in[3];
    const float* W1        = (const float*)d_in[4];
    const float* b1        = (const float*)d_in[5];
    const float* W2        = (const float*)d_in[6];
    const float* b2        = (const float*)d_in[7];
    float*       out       = (float*)d_out;

    float* ent = (float*)d_ws;                       // [256*768]  = 768 KB
    float* h   = (float*)d_ws + (size_t)RTOT * HH;   // [256*1000] = 1000 KB

    mlp1_kernel<<<dim3(RTOT, 2), dim3(256), 0, stream>>>(
        ent_emb, W1, b1, b2, h, ent);

    mlp2_kernel<<<dim3(12 * KS, BB), dim3(256), 0, stream>>>(
        h, W2, ent);

    gather_scatter_kernel<<<dim3(BB * SS / 4), dim3(256), 0, stream>>>(
        input_ids, ent_mask, word_emb, ent, out);
}